// Round 1
// baseline (5460.172 us; speedup 1.0000x reference)
//
#include <hip/hip_runtime.h>
#include <math.h>

// Problem constants (fixed by setup_inputs)
#define NCH 128
#define IMW 640
#define IMH 480
#define HW (IMW * IMH)
#define THREADS 512
#define WPB (THREADS / 64)   // waves per block

// state layout in d_ws (doubles)
#define S_R    0   // 9: current R (row-major)
#define S_T    9   // 3: current t
#define S_RC   12  // 9: candidate R
#define S_TC   21  // 3: candidate t
#define S_LAM  24
#define S_LR   25
#define S_PREV 26
#define S_TOTAL 32

__device__ __forceinline__ float sel6(int k, float v0, float v1, float v2,
                                      float v3, float v4, float v5) {
  float r = v0;
  r = (k == 1) ? v1 : r;
  r = (k == 2) ? v2 : r;
  r = (k == 3) ? v3 : r;
  r = (k == 4) ? v4 : r;
  r = (k == 5) ? v5 : r;
  return r;
}

struct ProjR {
  float x, y, z;
  int pix;
  bool m;
};

__device__ __forceinline__ ProjR project_pt(const float* __restrict__ pts, int n,
                                            const float R[9], const float T[3],
                                            const float Kv[9]) {
  float px = pts[3 * n + 0], py = pts[3 * n + 1], pz = pts[3 * n + 2];
  ProjR o;
  o.x = R[0] * px + R[1] * py + R[2] * pz + T[0];
  o.y = R[3] * px + R[4] * py + R[5] * pz + T[1];
  o.z = R[6] * px + R[7] * py + R[8] * pz + T[2];
  float pr0 = Kv[0] * o.x + Kv[1] * o.y + Kv[2] * o.z;
  float pr1 = Kv[3] * o.x + Kv[4] * o.y + Kv[5] * o.z;
  float pr2 = Kv[6] * o.x + Kv[7] * o.y + Kv[8] * o.z;
  float u = fminf(fmaxf(pr0 / pr2, -1000000.0f), 1000000.0f);
  float v = fminf(fmaxf(pr1 / pr2, -1000000.0f), 1000000.0f);
  int p2x = (int)rintf(u) - 1;   // round-half-even matches jnp.round
  int p2y = (int)rintf(v) - 1;
  o.m = (p2x >= 0) && (p2y >= 0) && (p2x < IMW) && (p2y < IMH);
  // Hf==height, Wf==width -> rows = clip(p2y,0,H-1), cols = clip(p2x,0,W-1)
  int r = min(max(p2y, 0), IMH - 1);
  int c = min(max(p2x, 0), IMW - 1);
  o.pix = r * IMW + c;
  return o;
}

__global__ void init_kernel(const float* __restrict__ Rin,
                            const float* __restrict__ tin,
                            double* __restrict__ st) {
  int i = threadIdx.x;
  if (i < 9) { st[S_R + i] = (double)Rin[i]; st[S_RC + i] = (double)Rin[i]; }
  if (i < 3) { st[S_T + i] = (double)tin[i]; st[S_TC + i] = (double)tin[i]; }
  if (i == 0) { st[S_LAM] = 0.01; st[S_LR] = 1.0; st[S_PREV] = 0.0; }
}

// One wave per point (grid-stride). Lane l covers channels l and l+64.
// Per-point channel sums reduced across the wave, then lane q<27 accumulates
// quantity q (6 Grad + 21 upper-tri Hess) in double; block partials written
// deterministically, reduced in solve_kernel.
__global__ __launch_bounds__(THREADS) void grad_kernel(
    const float* __restrict__ pts, const float* __restrict__ fref,
    const float* __restrict__ fm, const float* __restrict__ gxm,
    const float* __restrict__ gym, const float* __restrict__ Kmat,
    const double* __restrict__ st, double* __restrict__ gpart, int N) {
  const int lane = threadIdx.x & 63;
  const int wib = threadIdx.x >> 6;
  const int gw = blockIdx.x * WPB + wib;
  const int nw = gridDim.x * WPB;

  float R[9], T[3], Kv[9];
#pragma unroll
  for (int i = 0; i < 9; ++i) { R[i] = (float)st[S_R + i]; Kv[i] = Kmat[i]; }
#pragma unroll
  for (int i = 0; i < 3; ++i) T[i] = (float)st[S_T + i];
  const float fx = Kv[0], fy = Kv[4];

  // lane -> (kq,lq): q<6 => Grad[q]; q in [6,27) => Hess upper-tri pair
  int kq = 0, lq = 0;
  if (lane < 6) {
    kq = lane; lq = lane;
  } else if (lane < 27) {
    int q = lane - 6, k = 0;
    while (q >= 6 - k) { q -= 6 - k; ++k; }
    kq = k; lq = k + q;
  }

  double acc = 0.0;

  for (int n = gw; n < N; n += nw) {
    ProjR p = project_pt(pts, n, R, T, Kv);
    if (!p.m) continue;  // masked-out: zero contribution (wave-uniform)
    float Zs = (fabsf(p.z) > 1e-6f) ? p.z : 1e-6f;
    float iz = 1.0f / Zs;
    float j00 = fx * iz;
    float j02 = -fx * p.x * iz * iz;
    float j11 = fy * iz;
    float j12 = -fy * p.y * iz * iz;
    // A = J_px_p @ [I | -skew(p3)]  (2 x 6)
    float A0[6] = {j00, 0.0f, j02, j02 * p.y, j00 * p.z - j02 * p.x, -j00 * p.y};
    float A1[6] = {0.0f, j11, j12, -j11 * p.z + j12 * p.y, -j12 * p.x, j11 * p.x};

    const size_t base = (size_t)p.pix;
    const int c0 = lane, c1 = lane + 64;
    float f0 = fm[(size_t)c0 * HW + base], f1 = fm[(size_t)c1 * HW + base];
    float gx0 = gxm[(size_t)c0 * HW + base], gx1 = gxm[(size_t)c1 * HW + base];
    float gy0 = gym[(size_t)c0 * HW + base], gy1 = gym[(size_t)c1 * HW + base];
    float r0 = fref[(size_t)n * NCH + c0], r1 = fref[(size_t)n * NCH + c1];
    float e0 = f0 - r0, e1 = f1 - r1;

    float sxx = gx0 * gx0 + gx1 * gx1;
    float sxy = gx0 * gy0 + gx1 * gy1;
    float syy = gy0 * gy0 + gy1 * gy1;
    float sxe = gx0 * e0 + gx1 * e1;
    float sye = gy0 * e0 + gy1 * e1;
#pragma unroll
    for (int off = 32; off > 0; off >>= 1) {
      sxx += __shfl_xor(sxx, off);
      sxy += __shfl_xor(sxy, off);
      syy += __shfl_xor(syy, off);
      sxe += __shfl_xor(sxe, off);
      sye += __shfl_xor(sye, off);
    }
    float a0k = sel6(kq, A0[0], A0[1], A0[2], A0[3], A0[4], A0[5]);
    float a1k = sel6(kq, A1[0], A1[1], A1[2], A1[3], A1[4], A1[5]);
    float a0l = sel6(lq, A0[0], A0[1], A0[2], A0[3], A0[4], A0[5]);
    float a1l = sel6(lq, A1[0], A1[1], A1[2], A1[3], A1[4], A1[5]);
    float contrib;
    if (lane < 6)
      contrib = sxe * a0k + sye * a1k;                       // Grad
    else
      contrib = sxx * a0k * a0l + sxy * (a0k * a1l + a1k * a0l) +
                syy * a1k * a1l;                             // Hess
    if (lane < 27) acc += (double)contrib;
  }

  __shared__ double red[WPB][27];
  if (lane < 27) red[wib][lane] = acc;
  __syncthreads();
  if (wib == 0 && lane < 27) {
    double s = 0.0;
#pragma unroll
    for (int w = 0; w < WPB; ++w) s += red[w][lane];
    gpart[(size_t)blockIdx.x * 27 + lane] = s;
  }
}

// Cost of candidate pose (S_RC/S_TC). One wave per point; per-lane double
// accumulation, no per-point cross-lane reduce needed.
__global__ __launch_bounds__(THREADS) void cost_kernel(
    const float* __restrict__ pts, const float* __restrict__ fref,
    const float* __restrict__ fm, const float* __restrict__ Kmat,
    const double* __restrict__ st, double* __restrict__ cpart, int N) {
  const int lane = threadIdx.x & 63;
  const int wib = threadIdx.x >> 6;
  const int gw = blockIdx.x * WPB + wib;
  const int nw = gridDim.x * WPB;

  float R[9], T[3], Kv[9];
#pragma unroll
  for (int i = 0; i < 9; ++i) { R[i] = (float)st[S_RC + i]; Kv[i] = Kmat[i]; }
#pragma unroll
  for (int i = 0; i < 3; ++i) T[i] = (float)st[S_TC + i];

  double csum = 0.0, cnt = 0.0;
  for (int n = gw; n < N; n += nw) {
    ProjR p = project_pt(pts, n, R, T, Kv);
    if (!p.m) continue;
    const size_t base = (size_t)p.pix;
    const int c0 = lane, c1 = lane + 64;
    float f0 = fm[(size_t)c0 * HW + base], f1 = fm[(size_t)c1 * HW + base];
    float r0 = fref[(size_t)n * NCH + c0], r1 = fref[(size_t)n * NCH + c1];
    float e0 = f0 - r0, e1 = f1 - r1;
    csum += (double)(e0 * e0 + e1 * e1);
    if (lane == 0) cnt += 1.0;
  }
#pragma unroll
  for (int off = 32; off > 0; off >>= 1) {
    csum += __shfl_xor(csum, off);
    cnt += __shfl_xor(cnt, off);
  }
  __shared__ double redc[WPB][2];
  if (lane == 0) { redc[wib][0] = 0.5 * csum; redc[wib][1] = cnt; }
  __syncthreads();
  if (wib == 0 && lane == 0) {
    double s0 = 0.0, s1 = 0.0;
#pragma unroll
    for (int w = 0; w < WPB; ++w) { s0 += redc[w][0]; s1 += redc[w][1]; }
    cpart[(size_t)blockIdx.x * 2 + 0] = s0;
    cpart[(size_t)blockIdx.x * 2 + 1] = s1;
  }
}

// Reduce grad/hess partials, solve (Hess + lam*diag(diag+1e-9)) x = Grad,
// delta = -lr*x, so3exp, write candidate pose. 512 threads, deterministic.
__global__ void solve_kernel(const double* __restrict__ gpart, int GB,
                             double* __restrict__ st) {
  __shared__ double red[16][27];
  __shared__ double H27[27];
  int q = threadIdx.x & 31;
  int chunk = threadIdx.x >> 5;  // 0..15
  if (q < 27) {
    double s = 0.0;
    for (int b = chunk; b < GB; b += 16) s += gpart[(size_t)b * 27 + q];
    red[chunk][q] = s;
  }
  __syncthreads();
  if (threadIdx.x < 27) {
    double t = 0.0;
#pragma unroll
    for (int ch = 0; ch < 16; ++ch) t += red[ch][threadIdx.x];
    H27[threadIdx.x] = t;
  }
  __syncthreads();
  if (threadIdx.x == 0) {
    double Grad[6], Hs[6][6];
    for (int j = 0; j < 6; ++j) Grad[j] = H27[j];
    int qq = 0;
    for (int k = 0; k < 6; ++k)
      for (int l = k; l < 6; ++l) { Hs[k][l] = Hs[l][k] = H27[6 + qq]; ++qq; }
    double lam = st[S_LAM], lr = st[S_LR];
    double M[6][7];
    for (int i = 0; i < 6; ++i) {
      for (int j = 0; j < 6; ++j) M[i][j] = Hs[i][j];
      M[i][i] += lam * (Hs[i][i] + 1e-9);
      M[i][6] = Grad[i];
    }
    // Gaussian elimination with partial pivoting
    for (int c = 0; c < 6; ++c) {
      int piv = c;
      double mx = fabs(M[c][c]);
      for (int r = c + 1; r < 6; ++r) {
        double a = fabs(M[r][c]);
        if (a > mx) { mx = a; piv = r; }
      }
      if (piv != c)
        for (int j = 0; j < 7; ++j) {
          double tmp = M[c][j]; M[c][j] = M[piv][j]; M[piv][j] = tmp;
        }
      double pv = M[c][c];
      if (pv == 0.0) pv = 1e-30;
      for (int r = c + 1; r < 6; ++r) {
        double f = M[r][c] / pv;
        for (int j = c; j < 7; ++j) M[r][j] -= f * M[c][j];
      }
    }
    double xs[6];
    for (int i = 5; i >= 0; --i) {
      double v = M[i][6];
      for (int j = i + 1; j < 6; ++j) v -= M[i][j] * xs[j];
      double pv = M[i][i];
      if (pv == 0.0) pv = 1e-30;
      xs[i] = v / pv;
    }
    double dt[3] = {-lr * xs[0], -lr * xs[1], -lr * xs[2]};
    double dw[3] = {-lr * xs[3], -lr * xs[4], -lr * xs[5]};
    // so3exp
    double th2 = dw[0] * dw[0] + dw[1] * dw[1] + dw[2] * dw[2];
    double th = sqrt(th2 + 1e-24);
    double a, b;
    if (th < 1e-4) { a = 1.0 - th2 / 6.0; b = 0.5 - th2 / 24.0; }
    else { a = sin(th) / th; b = (1.0 - cos(th)) / (th2 + 1e-24); }
    double W[3][3] = {{0, -dw[2], dw[1]}, {dw[2], 0, -dw[0]}, {-dw[1], dw[0], 0}};
    double W2[3][3];
    for (int i = 0; i < 3; ++i)
      for (int j = 0; j < 3; ++j) {
        double s = 0.0;
        for (int k = 0; k < 3; ++k) s += W[i][k] * W[k][j];
        W2[i][j] = s;
      }
    double dr[3][3];
    for (int i = 0; i < 3; ++i)
      for (int j = 0; j < 3; ++j)
        dr[i][j] = ((i == j) ? 1.0 : 0.0) + a * W[i][j] + b * W2[i][j];
    // R_cand = dr @ R ; t_cand = dr @ t + dt
    for (int i = 0; i < 3; ++i) {
      for (int j = 0; j < 3; ++j) {
        double s = 0.0;
        for (int k = 0; k < 3; ++k) s += dr[i][k] * st[S_R + k * 3 + j];
        st[S_RC + i * 3 + j] = s;
      }
      double s = 0.0;
      for (int k = 0; k < 3; ++k) s += dr[i][k] * st[S_T + k];
      st[S_TC + i] = s + dt[i];
    }
  }
}

__global__ void update_kernel(const double* __restrict__ cpart, int CB,
                              double* __restrict__ st, float* __restrict__ out,
                              int is_init) {
  int lane = threadIdx.x;
  double cs = 0.0, cn = 0.0;
  for (int b = lane; b < CB; b += 64) {
    cs += cpart[(size_t)b * 2 + 0];
    cn += cpart[(size_t)b * 2 + 1];
  }
#pragma unroll
  for (int off = 32; off > 0; off >>= 1) {
    cs += __shfl_xor(cs, off);
    cn += __shfl_xor(cn, off);
  }
  if (lane == 0) {
    double nc = cs / fmax(cn, 1.0);
    if (is_init) {
      st[S_PREV] = nc;
    } else {
      bool accept = (nc <= st[S_PREV]);
      double lam = st[S_LAM] * (accept ? 0.1 : 10.0);
      st[S_LAM] = fmin(fmax(lam, 1e-6), 1e4);
      st[S_LR] = accept ? 1.0 : fmin(fmax(0.1 * st[S_LR], 1e-3), 1.0);
      if (accept) {
        for (int i = 0; i < 9; ++i) st[S_R + i] = st[S_RC + i];
        for (int i = 0; i < 3; ++i) st[S_T + i] = st[S_TC + i];
        st[S_PREV] = nc;
      }
    }
    for (int i = 0; i < 9; ++i) out[i] = (float)st[S_R + i];
    for (int i = 0; i < 3; ++i) out[9 + i] = (float)st[S_T + i];
  }
}

extern "C" void kernel_launch(void* const* d_in, const int* in_sizes, int n_in,
                              void* d_out, int out_size, void* d_ws, size_t ws_size,
                              hipStream_t stream) {
  const float* pts  = (const float*)d_in[0];
  const float* fref = (const float*)d_in[1];
  const float* fm   = (const float*)d_in[2];
  const float* gxm  = (const float*)d_in[3];
  const float* gym  = (const float*)d_in[4];
  const float* Kmat = (const float*)d_in[5];
  const float* Rin  = (const float*)d_in[6];
  const float* tin  = (const float*)d_in[7];
  const int N = in_sizes[0] / 3;

  // pick block counts that fit the workspace (ws_size is constant per session)
  int GB = 512, CB = 512;
  size_t need = (size_t)(S_TOTAL + GB * 27 + CB * 2) * sizeof(double);
  if (ws_size < need) { GB = 64; CB = 64; }

  double* st = (double*)d_ws;
  double* gpart = st + S_TOTAL;
  double* cpart = gpart + (size_t)GB * 27;
  float* out = (float*)d_out;

  init_kernel<<<1, 64, 0, stream>>>(Rin, tin, st);
  cost_kernel<<<CB, THREADS, 0, stream>>>(pts, fref, fm, Kmat, st, cpart, N);
  update_kernel<<<1, 64, 0, stream>>>(cpart, CB, st, out, 1);
  for (int it = 0; it < 10; ++it) {
    grad_kernel<<<GB, THREADS, 0, stream>>>(pts, fref, fm, gxm, gym, Kmat, st,
                                            gpart, N);
    solve_kernel<<<1, 512, 0, stream>>>(gpart, GB, st);
    cost_kernel<<<CB, THREADS, 0, stream>>>(pts, fref, fm, Kmat, st, cpart, N);
    update_kernel<<<1, 64, 0, stream>>>(cpart, CB, st, out, 0);
  }
}

// Round 2
// 1128.727 us; speedup vs baseline: 4.8375x; 4.8375x over previous
//
#include <hip/hip_runtime.h>
#include <math.h>

// Problem constants (fixed by setup_inputs)
#define NCH 128
#define IMW 640
#define IMH 480
#define HW (IMW * IMH)
#define THREADS 512
#define WPB (THREADS / 64)   // waves per block
#define GBLK 512             // grad/cost partial blocks

// state layout in d_ws (doubles)
#define S_R    0   // 9: current R (row-major)
#define S_T    9   // 3: current t
#define S_RC   12  // 9: candidate R
#define S_TC   21  // 3: candidate t
#define S_LAM  24
#define S_LR   25
#define S_PREV 26
#define S_TOTAL 32

__device__ __forceinline__ float sel6(int k, float v0, float v1, float v2,
                                      float v3, float v4, float v5) {
  float r = v0;
  r = (k == 1) ? v1 : r;
  r = (k == 2) ? v2 : r;
  r = (k == 3) ? v3 : r;
  r = (k == 4) ? v4 : r;
  r = (k == 5) ? v5 : r;
  return r;
}

struct ProjR {
  float x, y, z;
  int pix;
  bool m;
};

__device__ __forceinline__ ProjR project_pt(const float* __restrict__ pts, int n,
                                            const float R[9], const float T[3],
                                            const float Kv[9]) {
  float px = pts[3 * n + 0], py = pts[3 * n + 1], pz = pts[3 * n + 2];
  ProjR o;
  o.x = R[0] * px + R[1] * py + R[2] * pz + T[0];
  o.y = R[3] * px + R[4] * py + R[5] * pz + T[1];
  o.z = R[6] * px + R[7] * py + R[8] * pz + T[2];
  float pr0 = Kv[0] * o.x + Kv[1] * o.y + Kv[2] * o.z;
  float pr1 = Kv[3] * o.x + Kv[4] * o.y + Kv[5] * o.z;
  float pr2 = Kv[6] * o.x + Kv[7] * o.y + Kv[8] * o.z;
  float u = fminf(fmaxf(pr0 / pr2, -1000000.0f), 1000000.0f);
  float v = fminf(fmaxf(pr1 / pr2, -1000000.0f), 1000000.0f);
  int p2x = (int)rintf(u) - 1;   // round-half-even matches jnp.round
  int p2y = (int)rintf(v) - 1;
  o.m = (p2x >= 0) && (p2y >= 0) && (p2x < IMW) && (p2y < IMH);
  int r = min(max(p2y, 0), IMH - 1);
  int c = min(max(p2x, 0), IMW - 1);
  o.pix = r * IMW + c;
  return o;
}

// Per-point 2x6 Jacobian rows A0, A1
__device__ __forceinline__ void jac_rows(const ProjR& p, float fx, float fy,
                                         float A0[6], float A1[6]) {
  float Zs = (fabsf(p.z) > 1e-6f) ? p.z : 1e-6f;
  float iz = 1.0f / Zs;
  float j00 = fx * iz;
  float j02 = -fx * p.x * iz * iz;
  float j11 = fy * iz;
  float j12 = -fy * p.y * iz * iz;
  A0[0] = j00; A0[1] = 0.0f; A0[2] = j02;
  A0[3] = j02 * p.y; A0[4] = j00 * p.z - j02 * p.x; A0[5] = -j00 * p.y;
  A1[0] = 0.0f; A1[1] = j11; A1[2] = j12;
  A1[3] = -j11 * p.z + j12 * p.y; A1[4] = -j12 * p.x; A1[5] = j11 * p.x;
}

__global__ void init_kernel(const float* __restrict__ Rin,
                            const float* __restrict__ tin,
                            double* __restrict__ st) {
  int i = threadIdx.x;
  if (i < 9) { st[S_R + i] = (double)Rin[i]; st[S_RC + i] = (double)Rin[i]; }
  if (i < 3) { st[S_T + i] = (double)tin[i]; st[S_TC + i] = (double)tin[i]; }
  if (i == 0) { st[S_LAM] = 0.01; st[S_LR] = 1.0; st[S_PREV] = 0.0; }
}

// ---- (C,H,W) -> (H,W,C) transpose, 64-pixel tiles, LDS staged ----
__global__ __launch_bounds__(256) void transpose_kernel(
    const float* __restrict__ in, float* __restrict__ out) {
  __shared__ float tile[64][NCH + 1];  // +1 pad: break 128-stride bank alias
  const int pix0 = blockIdx.x * 64;
  // load: float4 along pixels, coalesced 256B per 16 lanes
  for (int k = threadIdx.x; k < 64 * NCH / 4; k += 256) {
    int c = k >> 4;            // 16 float4 per channel row
    int p4 = (k & 15) * 4;
    float4 v = ((const float4*)(in + (size_t)c * HW + pix0))[k & 15];
    tile[p4 + 0][c] = v.x;
    tile[p4 + 1][c] = v.y;
    tile[p4 + 2][c] = v.z;
    tile[p4 + 3][c] = v.w;
  }
  __syncthreads();
  // store: float4 along channels, coalesced 512B per pixel
  for (int k = threadIdx.x; k < 64 * NCH / 4; k += 256) {
    int px = k >> 5;           // 32 float4 per pixel
    int c4 = (k & 31) * 4;
    float4 v = make_float4(tile[px][c4], tile[px][c4 + 1], tile[px][c4 + 2],
                           tile[px][c4 + 3]);
    ((float4*)(out + (size_t)(pix0 + px) * NCH))[k & 31] = v;
  }
}

// ---- fast path: gather from (H,W,C) transposed maps, float2 per lane ----
__global__ __launch_bounds__(THREADS) void grad_kernel_t(
    const float* __restrict__ pts, const float* __restrict__ fref,
    const float* __restrict__ tf, const float* __restrict__ tgx,
    const float* __restrict__ tgy, const float* __restrict__ Kmat,
    const double* __restrict__ st, double* __restrict__ gpart, int N) {
  const int lane = threadIdx.x & 63;
  const int wib = threadIdx.x >> 6;
  const int gw = blockIdx.x * WPB + wib;
  const int nw = gridDim.x * WPB;

  float R[9], T[3], Kv[9];
#pragma unroll
  for (int i = 0; i < 9; ++i) { R[i] = (float)st[S_R + i]; Kv[i] = Kmat[i]; }
#pragma unroll
  for (int i = 0; i < 3; ++i) T[i] = (float)st[S_T + i];
  const float fx = Kv[0], fy = Kv[4];

  int kq = 0, lq = 0;
  if (lane < 6) {
    kq = lane; lq = lane;
  } else if (lane < 27) {
    int q = lane - 6, k = 0;
    while (q >= 6 - k) { q -= 6 - k; ++k; }
    kq = k; lq = k + q;
  }

  double acc = 0.0;

  for (int n = gw; n < N; n += nw) {
    ProjR p = project_pt(pts, n, R, T, Kv);
    if (!p.m) continue;  // wave-uniform
    float A0[6], A1[6];
    jac_rows(p, fx, fy, A0, A1);

    const size_t base = (size_t)p.pix * NCH + 2 * lane;
    float2 f  = *(const float2*)(tf + base);
    float2 gx = *(const float2*)(tgx + base);
    float2 gy = *(const float2*)(tgy + base);
    float2 fr = *(const float2*)(fref + (size_t)n * NCH + 2 * lane);
    float e0 = f.x - fr.x, e1 = f.y - fr.y;

    float sxx = gx.x * gx.x + gx.y * gx.y;
    float sxy = gx.x * gy.x + gx.y * gy.y;
    float syy = gy.x * gy.x + gy.y * gy.y;
    float sxe = gx.x * e0 + gx.y * e1;
    float sye = gy.x * e0 + gy.y * e1;
#pragma unroll
    for (int off = 32; off > 0; off >>= 1) {
      sxx += __shfl_xor(sxx, off);
      sxy += __shfl_xor(sxy, off);
      syy += __shfl_xor(syy, off);
      sxe += __shfl_xor(sxe, off);
      sye += __shfl_xor(sye, off);
    }
    float a0k = sel6(kq, A0[0], A0[1], A0[2], A0[3], A0[4], A0[5]);
    float a1k = sel6(kq, A1[0], A1[1], A1[2], A1[3], A1[4], A1[5]);
    float a0l = sel6(lq, A0[0], A0[1], A0[2], A0[3], A0[4], A0[5]);
    float a1l = sel6(lq, A1[0], A1[1], A1[2], A1[3], A1[4], A1[5]);
    float contrib;
    if (lane < 6)
      contrib = sxe * a0k + sye * a1k;
    else
      contrib = sxx * a0k * a0l + sxy * (a0k * a1l + a1k * a0l) +
                syy * a1k * a1l;
    if (lane < 27) acc += (double)contrib;
  }

  __shared__ double red[WPB][27];
  if (lane < 27) red[wib][lane] = acc;
  __syncthreads();
  if (wib == 0 && lane < 27) {
    double s = 0.0;
#pragma unroll
    for (int w = 0; w < WPB; ++w) s += red[w][lane];
    gpart[(size_t)blockIdx.x * 27 + lane] = s;
  }
}

__global__ __launch_bounds__(THREADS) void cost_kernel_t(
    const float* __restrict__ pts, const float* __restrict__ fref,
    const float* __restrict__ tf, const float* __restrict__ Kmat,
    const double* __restrict__ st, double* __restrict__ cpart, int N) {
  const int lane = threadIdx.x & 63;
  const int wib = threadIdx.x >> 6;
  const int gw = blockIdx.x * WPB + wib;
  const int nw = gridDim.x * WPB;

  float R[9], T[3], Kv[9];
#pragma unroll
  for (int i = 0; i < 9; ++i) { R[i] = (float)st[S_RC + i]; Kv[i] = Kmat[i]; }
#pragma unroll
  for (int i = 0; i < 3; ++i) T[i] = (float)st[S_TC + i];

  double csum = 0.0, cnt = 0.0;
  for (int n = gw; n < N; n += nw) {
    ProjR p = project_pt(pts, n, R, T, Kv);
    if (!p.m) continue;
    const size_t base = (size_t)p.pix * NCH + 2 * lane;
    float2 f  = *(const float2*)(tf + base);
    float2 fr = *(const float2*)(fref + (size_t)n * NCH + 2 * lane);
    float e0 = f.x - fr.x, e1 = f.y - fr.y;
    csum += (double)(e0 * e0 + e1 * e1);
    if (lane == 0) cnt += 1.0;
  }
#pragma unroll
  for (int off = 32; off > 0; off >>= 1) {
    csum += __shfl_xor(csum, off);
    cnt += __shfl_xor(cnt, off);
  }
  __shared__ double redc[WPB][2];
  if (lane == 0) { redc[wib][0] = 0.5 * csum; redc[wib][1] = cnt; }
  __syncthreads();
  if (wib == 0 && lane == 0) {
    double s0 = 0.0, s1 = 0.0;
#pragma unroll
    for (int w = 0; w < WPB; ++w) { s0 += redc[w][0]; s1 += redc[w][1]; }
    cpart[(size_t)blockIdx.x * 2 + 0] = s0;
    cpart[(size_t)blockIdx.x * 2 + 1] = s1;
  }
}

// ---- fallback path: gather from (C,H,W) original layout ----
__global__ __launch_bounds__(THREADS) void grad_kernel(
    const float* __restrict__ pts, const float* __restrict__ fref,
    const float* __restrict__ fm, const float* __restrict__ gxm,
    const float* __restrict__ gym, const float* __restrict__ Kmat,
    const double* __restrict__ st, double* __restrict__ gpart, int N) {
  const int lane = threadIdx.x & 63;
  const int wib = threadIdx.x >> 6;
  const int gw = blockIdx.x * WPB + wib;
  const int nw = gridDim.x * WPB;

  float R[9], T[3], Kv[9];
#pragma unroll
  for (int i = 0; i < 9; ++i) { R[i] = (float)st[S_R + i]; Kv[i] = Kmat[i]; }
#pragma unroll
  for (int i = 0; i < 3; ++i) T[i] = (float)st[S_T + i];
  const float fx = Kv[0], fy = Kv[4];

  int kq = 0, lq = 0;
  if (lane < 6) {
    kq = lane; lq = lane;
  } else if (lane < 27) {
    int q = lane - 6, k = 0;
    while (q >= 6 - k) { q -= 6 - k; ++k; }
    kq = k; lq = k + q;
  }

  double acc = 0.0;

  for (int n = gw; n < N; n += nw) {
    ProjR p = project_pt(pts, n, R, T, Kv);
    if (!p.m) continue;
    float A0[6], A1[6];
    jac_rows(p, fx, fy, A0, A1);

    const size_t base = (size_t)p.pix;
    const int c0 = lane, c1 = lane + 64;
    float f0 = fm[(size_t)c0 * HW + base], f1 = fm[(size_t)c1 * HW + base];
    float gx0 = gxm[(size_t)c0 * HW + base], gx1 = gxm[(size_t)c1 * HW + base];
    float gy0 = gym[(size_t)c0 * HW + base], gy1 = gym[(size_t)c1 * HW + base];
    float r0 = fref[(size_t)n * NCH + c0], r1 = fref[(size_t)n * NCH + c1];
    float e0 = f0 - r0, e1 = f1 - r1;

    float sxx = gx0 * gx0 + gx1 * gx1;
    float sxy = gx0 * gy0 + gx1 * gy1;
    float syy = gy0 * gy0 + gy1 * gy1;
    float sxe = gx0 * e0 + gx1 * e1;
    float sye = gy0 * e0 + gy1 * e1;
#pragma unroll
    for (int off = 32; off > 0; off >>= 1) {
      sxx += __shfl_xor(sxx, off);
      sxy += __shfl_xor(sxy, off);
      syy += __shfl_xor(syy, off);
      sxe += __shfl_xor(sxe, off);
      sye += __shfl_xor(sye, off);
    }
    float a0k = sel6(kq, A0[0], A0[1], A0[2], A0[3], A0[4], A0[5]);
    float a1k = sel6(kq, A1[0], A1[1], A1[2], A1[3], A1[4], A1[5]);
    float a0l = sel6(lq, A0[0], A0[1], A0[2], A0[3], A0[4], A0[5]);
    float a1l = sel6(lq, A1[0], A1[1], A1[2], A1[3], A1[4], A1[5]);
    float contrib;
    if (lane < 6)
      contrib = sxe * a0k + sye * a1k;
    else
      contrib = sxx * a0k * a0l + sxy * (a0k * a1l + a1k * a0l) +
                syy * a1k * a1l;
    if (lane < 27) acc += (double)contrib;
  }

  __shared__ double red[WPB][27];
  if (lane < 27) red[wib][lane] = acc;
  __syncthreads();
  if (wib == 0 && lane < 27) {
    double s = 0.0;
#pragma unroll
    for (int w = 0; w < WPB; ++w) s += red[w][lane];
    gpart[(size_t)blockIdx.x * 27 + lane] = s;
  }
}

__global__ __launch_bounds__(THREADS) void cost_kernel(
    const float* __restrict__ pts, const float* __restrict__ fref,
    const float* __restrict__ fm, const float* __restrict__ Kmat,
    const double* __restrict__ st, double* __restrict__ cpart, int N) {
  const int lane = threadIdx.x & 63;
  const int wib = threadIdx.x >> 6;
  const int gw = blockIdx.x * WPB + wib;
  const int nw = gridDim.x * WPB;

  float R[9], T[3], Kv[9];
#pragma unroll
  for (int i = 0; i < 9; ++i) { R[i] = (float)st[S_RC + i]; Kv[i] = Kmat[i]; }
#pragma unroll
  for (int i = 0; i < 3; ++i) T[i] = (float)st[S_TC + i];

  double csum = 0.0, cnt = 0.0;
  for (int n = gw; n < N; n += nw) {
    ProjR p = project_pt(pts, n, R, T, Kv);
    if (!p.m) continue;
    const size_t base = (size_t)p.pix;
    const int c0 = lane, c1 = lane + 64;
    float f0 = fm[(size_t)c0 * HW + base], f1 = fm[(size_t)c1 * HW + base];
    float r0 = fref[(size_t)n * NCH + c0], r1 = fref[(size_t)n * NCH + c1];
    float e0 = f0 - r0, e1 = f1 - r1;
    csum += (double)(e0 * e0 + e1 * e1);
    if (lane == 0) cnt += 1.0;
  }
#pragma unroll
  for (int off = 32; off > 0; off >>= 1) {
    csum += __shfl_xor(csum, off);
    cnt += __shfl_xor(cnt, off);
  }
  __shared__ double redc[WPB][2];
  if (lane == 0) { redc[wib][0] = 0.5 * csum; redc[wib][1] = cnt; }
  __syncthreads();
  if (wib == 0 && lane == 0) {
    double s0 = 0.0, s1 = 0.0;
#pragma unroll
    for (int w = 0; w < WPB; ++w) { s0 += redc[w][0]; s1 += redc[w][1]; }
    cpart[(size_t)blockIdx.x * 2 + 0] = s0;
    cpart[(size_t)blockIdx.x * 2 + 1] = s1;
  }
}

// Reduce grad/hess partials, LM solve, so3exp, write candidate pose.
__global__ void solve_kernel(const double* __restrict__ gpart, int GB,
                             double* __restrict__ st) {
  __shared__ double red[16][27];
  __shared__ double H27[27];
  int q = threadIdx.x & 31;
  int chunk = threadIdx.x >> 5;  // 0..15
  if (q < 27) {
    double s = 0.0;
    for (int b = chunk; b < GB; b += 16) s += gpart[(size_t)b * 27 + q];
    red[chunk][q] = s;
  }
  __syncthreads();
  if (threadIdx.x < 27) {
    double t = 0.0;
#pragma unroll
    for (int ch = 0; ch < 16; ++ch) t += red[ch][threadIdx.x];
    H27[threadIdx.x] = t;
  }
  __syncthreads();
  if (threadIdx.x == 0) {
    double Grad[6], Hs[6][6];
    for (int j = 0; j < 6; ++j) Grad[j] = H27[j];
    int qq = 0;
    for (int k = 0; k < 6; ++k)
      for (int l = k; l < 6; ++l) { Hs[k][l] = Hs[l][k] = H27[6 + qq]; ++qq; }
    double lam = st[S_LAM], lr = st[S_LR];
    double M[6][7];
    for (int i = 0; i < 6; ++i) {
      for (int j = 0; j < 6; ++j) M[i][j] = Hs[i][j];
      M[i][i] += lam * (Hs[i][i] + 1e-9);
      M[i][6] = Grad[i];
    }
    for (int c = 0; c < 6; ++c) {
      int piv = c;
      double mx = fabs(M[c][c]);
      for (int r = c + 1; r < 6; ++r) {
        double a = fabs(M[r][c]);
        if (a > mx) { mx = a; piv = r; }
      }
      if (piv != c)
        for (int j = 0; j < 7; ++j) {
          double tmp = M[c][j]; M[c][j] = M[piv][j]; M[piv][j] = tmp;
        }
      double pv = M[c][c];
      if (pv == 0.0) pv = 1e-30;
      for (int r = c + 1; r < 6; ++r) {
        double f = M[r][c] / pv;
        for (int j = c; j < 7; ++j) M[r][j] -= f * M[c][j];
      }
    }
    double xs[6];
    for (int i = 5; i >= 0; --i) {
      double v = M[i][6];
      for (int j = i + 1; j < 6; ++j) v -= M[i][j] * xs[j];
      double pv = M[i][i];
      if (pv == 0.0) pv = 1e-30;
      xs[i] = v / pv;
    }
    double dt[3] = {-lr * xs[0], -lr * xs[1], -lr * xs[2]};
    double dw[3] = {-lr * xs[3], -lr * xs[4], -lr * xs[5]};
    double th2 = dw[0] * dw[0] + dw[1] * dw[1] + dw[2] * dw[2];
    double th = sqrt(th2 + 1e-24);
    double a, b;
    if (th < 1e-4) { a = 1.0 - th2 / 6.0; b = 0.5 - th2 / 24.0; }
    else { a = sin(th) / th; b = (1.0 - cos(th)) / (th2 + 1e-24); }
    double W[3][3] = {{0, -dw[2], dw[1]}, {dw[2], 0, -dw[0]}, {-dw[1], dw[0], 0}};
    double W2[3][3];
    for (int i = 0; i < 3; ++i)
      for (int j = 0; j < 3; ++j) {
        double s = 0.0;
        for (int k = 0; k < 3; ++k) s += W[i][k] * W[k][j];
        W2[i][j] = s;
      }
    double dr[3][3];
    for (int i = 0; i < 3; ++i)
      for (int j = 0; j < 3; ++j)
        dr[i][j] = ((i == j) ? 1.0 : 0.0) + a * W[i][j] + b * W2[i][j];
    for (int i = 0; i < 3; ++i) {
      for (int j = 0; j < 3; ++j) {
        double s = 0.0;
        for (int k = 0; k < 3; ++k) s += dr[i][k] * st[S_R + k * 3 + j];
        st[S_RC + i * 3 + j] = s;
      }
      double s = 0.0;
      for (int k = 0; k < 3; ++k) s += dr[i][k] * st[S_T + k];
      st[S_TC + i] = s + dt[i];
    }
  }
}

__global__ void update_kernel(const double* __restrict__ cpart, int CB,
                              double* __restrict__ st, float* __restrict__ out,
                              int is_init) {
  int lane = threadIdx.x;
  double cs = 0.0, cn = 0.0;
  for (int b = lane; b < CB; b += 64) {
    cs += cpart[(size_t)b * 2 + 0];
    cn += cpart[(size_t)b * 2 + 1];
  }
#pragma unroll
  for (int off = 32; off > 0; off >>= 1) {
    cs += __shfl_xor(cs, off);
    cn += __shfl_xor(cn, off);
  }
  if (lane == 0) {
    double nc = cs / fmax(cn, 1.0);
    if (is_init) {
      st[S_PREV] = nc;
    } else {
      bool accept = (nc <= st[S_PREV]);
      double lam = st[S_LAM] * (accept ? 0.1 : 10.0);
      st[S_LAM] = fmin(fmax(lam, 1e-6), 1e4);
      st[S_LR] = accept ? 1.0 : fmin(fmax(0.1 * st[S_LR], 1e-3), 1.0);
      if (accept) {
        for (int i = 0; i < 9; ++i) st[S_R + i] = st[S_RC + i];
        for (int i = 0; i < 3; ++i) st[S_T + i] = st[S_TC + i];
        st[S_PREV] = nc;
      }
    }
    for (int i = 0; i < 9; ++i) out[i] = (float)st[S_R + i];
    for (int i = 0; i < 3; ++i) out[9 + i] = (float)st[S_T + i];
  }
}

extern "C" void kernel_launch(void* const* d_in, const int* in_sizes, int n_in,
                              void* d_out, int out_size, void* d_ws, size_t ws_size,
                              hipStream_t stream) {
  const float* pts  = (const float*)d_in[0];
  const float* fref = (const float*)d_in[1];
  const float* fm   = (const float*)d_in[2];
  const float* gxm  = (const float*)d_in[3];
  const float* gym  = (const float*)d_in[4];
  const float* Kmat = (const float*)d_in[5];
  const float* Rin  = (const float*)d_in[6];
  const float* tin  = (const float*)d_in[7];
  const int N = in_sizes[0] / 3;

  double* st = (double*)d_ws;
  double* gpart = st + S_TOTAL;
  double* cpart = gpart + (size_t)GBLK * 27;
  float* out = (float*)d_out;

  const size_t state_doubles = S_TOTAL + (size_t)GBLK * 27 + (size_t)GBLK * 2;
  const size_t map_floats = (size_t)HW * NCH;               // 39.32 M
  const size_t need_fast =
      state_doubles * sizeof(double) + 3 * map_floats * sizeof(float) + 256;

  init_kernel<<<1, 64, 0, stream>>>(Rin, tin, st);

  if (ws_size >= need_fast) {
    // fast path: transpose maps to (H,W,C) in workspace once per launch
    float* tf  = (float*)(st + state_doubles);
    float* tgx = tf + map_floats;
    float* tgy = tgx + map_floats;
    transpose_kernel<<<HW / 64, 256, 0, stream>>>(fm, tf);
    transpose_kernel<<<HW / 64, 256, 0, stream>>>(gxm, tgx);
    transpose_kernel<<<HW / 64, 256, 0, stream>>>(gym, tgy);

    cost_kernel_t<<<GBLK, THREADS, 0, stream>>>(pts, fref, tf, Kmat, st, cpart, N);
    update_kernel<<<1, 64, 0, stream>>>(cpart, GBLK, st, out, 1);
    for (int it = 0; it < 10; ++it) {
      grad_kernel_t<<<GBLK, THREADS, 0, stream>>>(pts, fref, tf, tgx, tgy, Kmat,
                                                  st, gpart, N);
      solve_kernel<<<1, 512, 0, stream>>>(gpart, GBLK, st);
      cost_kernel_t<<<GBLK, THREADS, 0, stream>>>(pts, fref, tf, Kmat, st, cpart, N);
      update_kernel<<<1, 64, 0, stream>>>(cpart, GBLK, st, out, 0);
    }
  } else {
    // fallback: gather directly from (C,H,W)
    cost_kernel<<<GBLK, THREADS, 0, stream>>>(pts, fref, fm, Kmat, st, cpart, N);
    update_kernel<<<1, 64, 0, stream>>>(cpart, GBLK, st, out, 1);
    for (int it = 0; it < 10; ++it) {
      grad_kernel<<<GBLK, THREADS, 0, stream>>>(pts, fref, fm, gxm, gym, Kmat,
                                                st, gpart, N);
      solve_kernel<<<1, 512, 0, stream>>>(gpart, GBLK, st);
      cost_kernel<<<GBLK, THREADS, 0, stream>>>(pts, fref, fm, Kmat, st, cpart, N);
      update_kernel<<<1, 64, 0, stream>>>(cpart, GBLK, st, out, 0);
    }
  }
}